// Round 13
// baseline (104.867 us; speedup 1.0000x reference)
//
#include <hip/hip_runtime.h>

#define B_ 256
#define L_ 512
#define D_ 768
#define C_ 10331
#define K_ 2304           // 3*D
#define GBK 64
#define NKIT (K_ / GBK)   // 36
#define NT 32             // W rows (out cols) per block
#define NBLK 323          // ceil(C_/NT)

using v8bf = __attribute__((ext_vector_type(8))) __bf16;
using v4f  = __attribute__((ext_vector_type(4))) float;

__device__ __forceinline__ unsigned short f2bf(float f) {
    unsigned int u = __float_as_uint(f);
    unsigned int r = (u + 0x7FFFu + ((u >> 16) & 1u)) >> 16;   // RNE
    return (unsigned short)r;
}

__device__ __forceinline__ void fma4(float4& a, float w, const float4& v) {
    a.x = fmaf(w, v.x, a.x); a.y = fmaf(w, v.y, a.y);
    a.z = fmaf(w, v.z, a.z); a.w = fmaf(w, v.w, a.w);
}

__device__ __forceinline__ void gload_lds16(const void* g, void* l) {
    __builtin_amdgcn_global_load_lds(
        (const __attribute__((address_space(1))) void*)g,
        (__attribute__((address_space(3))) void*)l, 16, 0, 0);
}

// ---------------------------------------------------------------------------
// Kernel 1: count-based gather + masked means -> feats (B, 3D) bf16.
// (unchanged; ~13 us)
// ---------------------------------------------------------------------------
__global__ __launch_bounds__(512) void feats_gather(
    const float* __restrict__ seq,        // (B, L, D)
    const int*   __restrict__ head_index, // (B, L)
    const int*   __restrict__ start,
    const int*   __restrict__ end,
    unsigned short* __restrict__ feats)   // (B, 3D) bf16
{
    const int b    = blockIdx.x;
    const int t    = threadIdx.x;
    const int lane = t & 63;
    const int wave = t >> 6;              // 0..7

    __shared__ int idx_sh[L_];
    __shared__ int cnt_sh[3][L_];
    __shared__ int list_sh[L_];
    __shared__ int nz_sh, nlist_sh;
    __shared__ float4 red_sh[8][3][192];  // 72 KB

    if (t == 0) nz_sh = 0;
    cnt_sh[0][t] = 0; cnt_sh[1][t] = 0; cnt_sh[2][t] = 0;
    const int v = head_index[b * L_ + t];
    idx_sh[t] = v;
    unsigned long long ball = __ballot(v != 0);
    __syncthreads();
    if (lane == 0) atomicAdd(&nz_sh, (int)__popcll(ball));
    __syncthreads();

    const int right_len = nz_sh;
    const int s = start[b];
    const int e = end[b];

    if (t < right_len) {
        int r = (t < s) ? 0 : ((t < e) ? 1 : 2);
        atomicAdd(&cnt_sh[r][v], 1);
    }
    __syncthreads();

    if (wave == 0) {
        int maskbits = 0, csum = 0;
        const int j0 = lane * 8;
        #pragma unroll
        for (int k = 0; k < 8; ++k) {
            int j = j0 + k;
            if (cnt_sh[0][j] | cnt_sh[1][j] | cnt_sh[2][j]) { maskbits |= (1 << k); ++csum; }
        }
        int incl = csum;
        #pragma unroll
        for (int off = 1; off < 64; off <<= 1) {
            int x = __shfl_up(incl, off, 64);
            if (lane >= off) incl += x;
        }
        int pos = incl - csum;
        #pragma unroll
        for (int k = 0; k < 8; ++k)
            if (maskbits & (1 << k)) list_sh[pos++] = j0 + k;
        if (lane == 63) nlist_sh = incl;
    }
    __syncthreads();

    const int nlist = nlist_sh;
    const int nl = s, nm = e - s, nr = right_len - e;
    const float rs0 = (nl > 0) ? 1.0f / (float)nl : 0.0f;
    const float rs1 = (nm > 0) ? 1.0f / (float)nm : 0.0f;
    const float rs2 = (nr > 0) ? 1.0f / (float)nr : 0.0f;

    const float4* seqb4 = reinterpret_cast<const float4*>(seq + (size_t)b * L_ * D_);

    float4 acc[3][3];
    #pragma unroll
    for (int r = 0; r < 3; ++r)
        #pragma unroll
        for (int jj = 0; jj < 3; ++jj)
            acc[r][jj] = make_float4(0.f, 0.f, 0.f, 0.f);

    int i = wave;
    for (; i + 8 < nlist; i += 16) {
        const int ja = list_sh[i], jb = list_sh[i + 8];
        const float4* rowa = seqb4 + (size_t)ja * 192;
        const float4* rowb = seqb4 + (size_t)jb * 192;
        float wa0 = (float)cnt_sh[0][ja] * rs0;
        float wa1 = (float)cnt_sh[1][ja] * rs1;
        float wa2 = (float)cnt_sh[2][ja] * rs2;
        float wb0 = (float)cnt_sh[0][jb] * rs0;
        float wb1 = (float)cnt_sh[1][jb] * rs1;
        float wb2 = (float)cnt_sh[2][jb] * rs2;
        #pragma unroll
        for (int jj = 0; jj < 3; ++jj) {
            float4 va = rowa[jj * 64 + lane];
            float4 vb = rowb[jj * 64 + lane];
            fma4(acc[0][jj], wa0, va); fma4(acc[1][jj], wa1, va); fma4(acc[2][jj], wa2, va);
            fma4(acc[0][jj], wb0, vb); fma4(acc[1][jj], wb1, vb); fma4(acc[2][jj], wb2, vb);
        }
    }
    if (i < nlist) {
        const int ja = list_sh[i];
        const float4* rowa = seqb4 + (size_t)ja * 192;
        float wa0 = (float)cnt_sh[0][ja] * rs0;
        float wa1 = (float)cnt_sh[1][ja] * rs1;
        float wa2 = (float)cnt_sh[2][ja] * rs2;
        #pragma unroll
        for (int jj = 0; jj < 3; ++jj) {
            float4 va = rowa[jj * 64 + lane];
            fma4(acc[0][jj], wa0, va); fma4(acc[1][jj], wa1, va); fma4(acc[2][jj], wa2, va);
        }
    }

    #pragma unroll
    for (int r = 0; r < 3; ++r)
        #pragma unroll
        for (int jj = 0; jj < 3; ++jj)
            red_sh[wave][r][jj * 64 + lane] = acc[r][jj];
    __syncthreads();

    for (int w = t; w < 576; w += 512) {
        int reg = w / 192, pos = w - reg * 192;
        float4 sum = red_sh[0][reg][pos];
        #pragma unroll
        for (int wv = 1; wv < 8; ++wv) {
            float4 x = red_sh[wv][reg][pos];
            sum.x += x.x; sum.y += x.y; sum.z += x.z; sum.w += x.w;
        }
        ushort4 u;
        u.x = f2bf(sum.x); u.y = f2bf(sum.y); u.z = f2bf(sum.z); u.w = f2bf(sum.w);
        *(ushort4*)(&feats[(size_t)b * K_ + reg * D_ + pos * 4]) = u;
    }
}

// ---------------------------------------------------------------------------
// Kernel 2: out = feats(bf16) @ W^T + bias, full K per block, direct write.
// Block = 32 W-rows (out cols) x 256 batch, 512 thr (8 waves, wave = 32
// M-rows). W rows streamed sequentially by exactly ONE block. W staged via
// global_load_lds into 3 LDS buffers, 2 tiles ahead, counted vmcnt(10/8) +
// raw s_barrier (never vmcnt(0) mid-loop). A-frags direct from L2, reg
// double-buffered, issued AFTER the gll (sched_barrier-pinned) so the A-wait
// leaves the W stream in flight. XOR-swizzled W LDS (both sides, rule #21).
// ---------------------------------------------------------------------------
__global__ __launch_bounds__(512, 4) void mfma_gemm(
    const unsigned short* __restrict__ A,  // (B_, K_) bf16
    const float* __restrict__ W,           // (C_, K_) fp32
    const float* __restrict__ bias,        // (C_,)
    float*       __restrict__ out)         // (B_, C_) f32
{
    __shared__ float Ws0[NT * GBK];   // 8 KB each
    __shared__ float Ws1[NT * GBK];
    __shared__ float Ws2[NT * GBK];

    const int t    = threadIdx.x;
    const int lane = t & 63;
    const int wave = t >> 6;          // 0..7 : 32-row M group

    // bijective XCD swizzle (m204), nwg = 323: q=40, r=3
    const int orig = blockIdx.x;
    const int xcd  = orig & 7;
    const int pos  = orig >> 3;
    const int swz  = (xcd < 3 ? xcd * 41 : 123 + (xcd - 3) * 40) + pos;
    const int col0 = swz * NT;

    const int frow = lane & 15;
    const int q    = lane >> 4;       // 0..3

    const unsigned short* a_base = A + (size_t)(wave * 32 + frow) * K_ + q * 8;
    const char* Wbytes = (const char*)W;

    v4f acc[2][2] = {};
    v8bf afA[2][2], afB[2][2];

    // per-lane staging coords (chunk id = t): row r, 16B-chunk c
    const int sg_r   = t >> 4;                      // 0..31
    const int sg_c   = t & 15;
    int sg_row = col0 + sg_r; if (sg_row > C_ - 1) sg_row = C_ - 1;
    const size_t sg_rowoff = (size_t)sg_row * (K_ * 4);
    const int sg_so  = (sg_c * 16) ^ ((sg_r & 7) << 4);   // pre-swizzled src
    const int sg_ldsbase = wave * 1024;                    // uniform per wave

#define STAGE(BUF, IT) { \
        gload_lds16(Wbytes + sg_rowoff + (size_t)(IT) * (GBK * 4) + sg_so, \
                    (char*)(BUF) + sg_ldsbase); }

#define LOAD_AF(DST, IT) { \
        _Pragma("unroll") \
        for (int m = 0; m < 2; ++m) \
            _Pragma("unroll") \
            for (int kk = 0; kk < 2; ++kk) \
                DST[m][kk] = *(const v8bf*)(a_base + (size_t)m * 16 * K_ + (IT) * GBK + kk * 32); }

#define COMPUTE(AF, BUF) { \
        v8bf bfr[2][2]; \
        _Pragma("unroll") \
        for (int n = 0; n < 2; ++n) { \
            int cl = n * 16 + frow; \
            int sw = (cl & 7) << 4; \
            const char* rb = (const char*)(BUF) + cl * 256; \
            _Pragma("unroll") \
            for (int kk = 0; kk < 2; ++kk) { \
                int y = kk * 128 + q * 32; \
                float4 lo = *(const float4*)(rb + ((y     ) ^ sw)); \
                float4 hi = *(const float4*)(rb + ((y + 16) ^ sw)); \
                v8bf bv; \
                bv[0] = (__bf16)lo.x; bv[1] = (__bf16)lo.y; \
                bv[2] = (__bf16)lo.z; bv[3] = (__bf16)lo.w; \
                bv[4] = (__bf16)hi.x; bv[5] = (__bf16)hi.y; \
                bv[6] = (__bf16)hi.z; bv[7] = (__bf16)hi.w; \
                bfr[n][kk] = bv; } } \
        _Pragma("unroll") \
        for (int kk = 0; kk < 2; ++kk) \
            _Pragma("unroll") \
            for (int m = 0; m < 2; ++m) \
                _Pragma("unroll") \
                for (int n = 0; n < 2; ++n) \
                    acc[m][n] = __builtin_amdgcn_mfma_f32_16x16x32_bf16(AF[m][kk], bfr[n][kk], acc[m][n], 0, 0, 0); }

// phase: wait gll(I) [vmcnt leaves newer in flight]; barrier; stage(I+2);
// load af(I+1); compute(I). All indices static via period-6 unroll.
#define PH(WAIT, AFC, AFN, BC, BS, SIT, LIT, DOSTG, DOLD) \
        asm volatile("s_waitcnt vmcnt(" #WAIT ")" ::: "memory"); \
        __builtin_amdgcn_s_barrier(); \
        __builtin_amdgcn_sched_barrier(0); \
        if (DOSTG) STAGE(BS, SIT) \
        __builtin_amdgcn_sched_barrier(0); \
        if (DOLD) LOAD_AF(AFN, LIT) \
        COMPUTE(AFC, BC)

    STAGE(Ws0, 0)
    STAGE(Ws1, 1)
    LOAD_AF(afA, 0)

    for (int it = 0; it < 30; it += 6) {
        PH(10, afA, afB, Ws0, Ws2, it + 2, it + 1, 1, 1)
        PH(10, afB, afA, Ws1, Ws0, it + 3, it + 2, 1, 1)
        PH(10, afA, afB, Ws2, Ws1, it + 4, it + 3, 1, 1)
        PH(10, afB, afA, Ws0, Ws2, it + 5, it + 4, 1, 1)
        PH(10, afA, afB, Ws1, Ws0, it + 6, it + 5, 1, 1)
        PH(10, afB, afA, Ws2, Ws1, it + 7, it + 6, 1, 1)
    }
    // phases 30..35 (tail: stages end at it=35, loads end at 35)
    PH(10, afA, afB, Ws0, Ws2, 32, 31, 1, 1)
    PH(10, afB, afA, Ws1, Ws0, 33, 32, 1, 1)
    PH(10, afA, afB, Ws2, Ws1, 34, 33, 1, 1)
    PH(10, afB, afA, Ws0, Ws2, 35, 34, 1, 1)
    PH(10, afA, afB, Ws1, Ws0,  0, 35, 0, 1)
    PH( 8, afB, afA, Ws2, Ws0,  0,  0, 0, 0)

    // ---- epilogue: direct out + bias ----
    const int crow = wave * 32 + q * 4;
    const int ccol = col0 + frow;
    #pragma unroll
    for (int n = 0; n < 2; ++n) {
        int col = ccol + n * 16;
        if (col < C_) {
            float bv = bias[col];
            #pragma unroll
            for (int m = 0; m < 2; ++m)
                #pragma unroll
                for (int r = 0; r < 4; ++r)
                    out[(size_t)(crow + m * 16 + r) * C_ + col] = acc[m][n][r] + bv;
        }
    }
#undef STAGE
#undef LOAD_AF
#undef COMPUTE
#undef PH
}

// ---------------------------------------------------------------------------
extern "C" void kernel_launch(void* const* d_in, const int* in_sizes, int n_in,
                              void* d_out, int out_size, void* d_ws, size_t ws_size,
                              hipStream_t stream) {
    const float* seq        = (const float*)d_in[0];
    const int*   head_index = (const int*)  d_in[1];
    const int*   start      = (const int*)  d_in[2];
    const int*   end        = (const int*)  d_in[3];
    const float* W          = (const float*)d_in[4];
    const float* bias       = (const float*)d_in[5];
    float*       out        = (float*)d_out;

    unsigned short* feats = (unsigned short*)d_ws;   // 1.18 MB

    feats_gather<<<dim3(B_), dim3(512), 0, stream>>>(seq, head_index, start, end, feats);
    mfma_gemm<<<dim3(NBLK), dim3(512), 0, stream>>>(feats, W, bias, out);
}